// Round 4
// baseline (100.623 us; speedup 1.0000x reference)
//
#include <hip/hip_runtime.h>
#include <cmath>

// Problem constants (fixed by the reference)
#define BB   64
#define TT   4096
#define DD1  256
#define DD2  128
#define UU   64
#define NT   16      // T tiles per batch row
#define TTILE 256    // rows per block
#define CH   64      // rows per chunk
#define NCH  4
#define THREADS 512

// LDS byte offsets. A buffers are LINEAR [64 rows][256 f32] (global_load_lds
// requires wave-uniform base + lane*16). Bank conflicts on the read side are
// handled by an XOR swizzle applied to the GLOBAL source and both readers:
// 16B slot (row, c) holds global col16 (c ^ (row&7)).
#define A0_OFF   0        // 65536 B
#define A1_OFF   65536    // 65536 B
#define BIAS_OFF 131072   // 64 f32
#define WCH_OFF  131328   // 64 f32 softmax weights
#define LOGP_OFF 131584   // 128 f32 logit partials
#define ML_OFF   132096   // [0]=m [1]=l [2]=rescale [3]=pad
#define RED_OFF  132112   // 1024 f32
#define LDS_BYTES 136208  // < 160 KiB

typedef short bf16x8 __attribute__((ext_vector_type(8)));
typedef float f32x4  __attribute__((ext_vector_type(4)));

#define GLOAD_LDS16(g, l) __builtin_amdgcn_global_load_lds( \
    (const __attribute__((address_space(1))) unsigned int*)(g), \
    (__attribute__((address_space(3))) unsigned int*)(l), 16, 0, 0)

__device__ __forceinline__ float tanh_fast(float x) {
    float ax = fabsf(x);
    float e  = __expf(-2.0f * ax);
    float t  = __fdividef(1.0f - e, 1.0f + e);
    return x < 0.0f ? -t : t;
}

// 8 f32 -> bf16 hi (truncate) + bf16 lo (exact residual, truncated)
__device__ __forceinline__ void cvt_hilo(float4 f0, float4 f1, bf16x8& h8, bf16x8& l8) {
    float x[8] = {f0.x, f0.y, f0.z, f0.w, f1.x, f1.y, f1.z, f1.w};
    union { unsigned u[4]; bf16x8 v; } H, L;
    #pragma unroll
    for (int p = 0; p < 4; ++p) {
        unsigned a = __float_as_uint(x[2*p]), b = __float_as_uint(x[2*p+1]);
        H.u[p] = (a >> 16) | (b & 0xffff0000u);
        float d0 = x[2*p]   - __uint_as_float(a & 0xffff0000u);
        float d1 = x[2*p+1] - __uint_as_float(b & 0xffff0000u);
        L.u[p] = (__float_as_uint(d0) >> 16) | (__float_as_uint(d1) & 0xffff0000u);
    }
    h8 = H.v; l8 = L.v;
}

// W1 column u, k = kb..kb+7 -> hi/lo bf16x8 B-frag (stride UU floats)
__device__ __forceinline__ void load_bfrag(const float* __restrict__ W1, int kb, int u,
                                           bf16x8& bh, bf16x8& bl) {
    float4 x0, x1;
    x0.x = W1[(kb + 0) * UU + u]; x0.y = W1[(kb + 1) * UU + u];
    x0.z = W1[(kb + 2) * UU + u]; x0.w = W1[(kb + 3) * UU + u];
    x1.x = W1[(kb + 4) * UU + u]; x1.y = W1[(kb + 5) * UU + u];
    x1.z = W1[(kb + 6) * UU + u]; x1.w = W1[(kb + 7) * UU + u];
    cvt_hilo(x0, x1, bh, bl);
}

__global__ __launch_bounds__(THREADS, 2)   // VGPR cap 256: B-frags (128) must fit
void caa_main(const float* __restrict__ seq, const float* __restrict__ ctx,
              const float* __restrict__ W1, const float* __restrict__ W2,
              float* __restrict__ part) {
    extern __shared__ __align__(16) char smem[];
    float* fml   = (float*)(smem + ML_OFF);
    float* fbias = (float*)(smem + BIAS_OFF);
    float* fwch  = (float*)(smem + WCH_OFF);
    float* flogp = (float*)(smem + LOGP_OFF);
    float* fred  = (float*)(smem + RED_OFF);

    const int tid = threadIdx.x;
    const int bx  = blockIdx.x;
    const int b    = bx >> 4, tile = bx & 15;
    const int w    = tid >> 6, l = tid & 63;
    const int l15  = l & 15,  kg = l >> 4;     // MFMA input: row/col = l15, k-octet = kg
    const int mf   = w & 3,   nh = w >> 2;     // wave -> m-frag (16 rows), u-half (32 u)
    const int w8   = w * 8;
    const int sw   = l15 & 7;                  // read-side XOR: (16mf+l15)&7 == l15&7

    const float* seqbase = seq + ((size_t)b * TT + (size_t)tile * TTILE) * DD1;

    // ---- issue chunk-0 staging immediately (HBM starts streaming) ----
    // per wave: 8 instrs, row = w8+i (row&7 == i), source col16 pre-swizzled by ^i
    {
        const char* gbase = (const char*)seqbase;
        char* dst = smem + A0_OFF;
        #pragma unroll
        for (int i = 0; i < 8; ++i) {
            int row = w8 + i;
            GLOAD_LDS16(gbase + (size_t)row * 1024 + ((l ^ i) << 4), dst + row * 1024);
        }
    }

    // ---- bias partials: 8 c-chunks x 64 u ----
    {
        int cq = tid >> 6;
        float s = 0.f;
        const float* cb = ctx + b * DD2 + cq * 16;
        const float* wb = W1 + (size_t)(DD1 + cq * 16) * UU + l;
        #pragma unroll
        for (int c = 0; c < 16; ++c) s = fmaf(cb[c], wb[c * UU], s);
        fred[cq * 64 + l] = s;
    }
    if (tid == 0) { fml[0] = -INFINITY; fml[1] = 0.f; }

    // ---- B-frags (W1_seq) resident in registers: 2 u-groups x 8 ks x hi/lo ----
    const int u0g = nh * 32 + l15, u1g = u0g + 16;
    bf16x8 b0h[8], b0l[8], b1h[8], b1l[8];
    #pragma unroll
    for (int ks = 0; ks < 8; ++ks) {
        int kb = ks * 32 + kg * 8;
        load_bfrag(W1, kb, u0g, b0h[ks], b0l[ks]);
        load_bfrag(W1, kb, u1g, b1h[ks], b1l[ks]);
    }

    asm volatile("s_waitcnt vmcnt(0)" ::: "memory");   // chunk 0 resident
    __syncthreads();
    if (tid < 64) {
        float s = 0.f;
        #pragma unroll
        for (int cq = 0; cq < 8; ++cq) s += fred[cq * 64 + tid];
        fbias[tid] = s;
    }
    __syncthreads();

    const float bias0 = fbias[u0g], bias1 = fbias[u1g];
    const float w20 = W2[u0g], w21 = W2[u1g];

    const int rowB = (16 * mf + l15) * 1024;   // A-frag row byte base (within buffer)
    float2 acc2 = make_float2(0.f, 0.f);       // weighted-sum acc: dims 2dp,2dp+1, quarter tq
    const int dp = tid & 127, tq = tid >> 7;
    const int c16a = dp >> 1, dOff = (dp & 1) * 8;   // accum-read swizzle pieces

    for (int c = 0; c < NCH; ++c) {
        const char* buf = smem + ((c & 1) ? A1_OFF : A0_OFF);
        // ---- issue next-chunk staging into the other buffer ----
        if (c < NCH - 1) {
            const char* gbase = (const char*)(seqbase + (size_t)(c + 1) * CH * DD1);
            char* dst = smem + (((c + 1) & 1) ? A1_OFF : A0_OFF);
            #pragma unroll
            for (int i = 0; i < 8; ++i) {
                int row = w8 + i;
                GLOAD_LDS16(gbase + (size_t)row * 1024 + ((l ^ i) << 4), dst + row * 1024);
            }
        }
        // ---- GEMM: read f32 A-frags (swizzled), cvt to hi/lo bf16, 6 MFMA/ks ----
        f32x4 acc0 = {0.f, 0.f, 0.f, 0.f}, acc1 = {0.f, 0.f, 0.f, 0.f};
        #pragma unroll
        for (int ks = 0; ks < 8; ++ks) {
            int g0 = ks * 8 + kg * 2;          // logical col16 of e=0..3
            float4 f0 = *(const float4*)(buf + rowB + (((g0    ) ^ sw) << 4));
            float4 f1 = *(const float4*)(buf + rowB + (((g0 + 1) ^ sw) << 4));
            bf16x8 ah, al;
            cvt_hilo(f0, f1, ah, al);
            acc0 = __builtin_amdgcn_mfma_f32_16x16x32_bf16(ah, b0h[ks], acc0, 0, 0, 0);
            acc1 = __builtin_amdgcn_mfma_f32_16x16x32_bf16(ah, b1h[ks], acc1, 0, 0, 0);
            acc0 = __builtin_amdgcn_mfma_f32_16x16x32_bf16(ah, b0l[ks], acc0, 0, 0, 0);
            acc1 = __builtin_amdgcn_mfma_f32_16x16x32_bf16(ah, b1l[ks], acc1, 0, 0, 0);
            acc0 = __builtin_amdgcn_mfma_f32_16x16x32_bf16(al, b0h[ks], acc0, 0, 0, 0);
            acc1 = __builtin_amdgcn_mfma_f32_16x16x32_bf16(al, b1h[ks], acc1, 0, 0, 0);
        }
        // ---- epilogue: tanh + W2 dot; reduce over u (lane&15) ----
        float lp[4];
        #pragma unroll
        for (int r = 0; r < 4; ++r) {
            float e0 = tanh_fast(acc0[r] + bias0);
            float e1 = tanh_fast(acc1[r] + bias1);
            float p  = e0 * w20 + e1 * w21;
            p += __shfl_xor(p, 1, 64);
            p += __shfl_xor(p, 2, 64);
            p += __shfl_xor(p, 4, 64);
            p += __shfl_xor(p, 8, 64);
            lp[r] = p;
        }
        if (l15 == 0) {      // C/D row = kg*4 + r within m-frag
            #pragma unroll
            for (int r = 0; r < 4; ++r) flogp[nh * 64 + 16 * mf + kg * 4 + r] = lp[r];
        }
        __syncthreads();                        // (A) logits visible
        // ---- online softmax over 64 chunk rows (wave 0) ----
        if (tid < 64) {
            float lg = flogp[tid] + flogp[64 + tid];
            float mx = lg;
            mx = fmaxf(mx, __shfl_xor(mx, 1, 64));
            mx = fmaxf(mx, __shfl_xor(mx, 2, 64));
            mx = fmaxf(mx, __shfl_xor(mx, 4, 64));
            mx = fmaxf(mx, __shfl_xor(mx, 8, 64));
            mx = fmaxf(mx, __shfl_xor(mx, 16, 64));
            mx = fmaxf(mx, __shfl_xor(mx, 32, 64));
            float mold = fml[0];
            float mnew = fmaxf(mold, mx);
            float rsc  = __expf(mold - mnew);   // first chunk: exp(-inf)=0
            float wv   = __expf(lg - mnew);
            float ss   = wv;
            ss += __shfl_xor(ss, 1, 64);
            ss += __shfl_xor(ss, 2, 64);
            ss += __shfl_xor(ss, 4, 64);
            ss += __shfl_xor(ss, 8, 64);
            ss += __shfl_xor(ss, 16, 64);
            ss += __shfl_xor(ss, 32, 64);
            fwch[tid] = wv;
            if (tid == 0) { fml[0] = mnew; fml[1] = fml[1] * rsc + ss; fml[2] = rsc; }
        }
        __syncthreads();                        // (B) weights visible
        // ---- weighted accumulation straight from the f32 LDS tile ----
        {
            float rsc = fml[2];
            acc2.x *= rsc; acc2.y *= rsc;
            #pragma unroll
            for (int i = 0; i < 16; ++i) {
                int row = tq * 16 + i;
                float wr = fwch[row];
                float2 a = *(const float2*)(buf + row * 1024 + ((c16a ^ (row & 7)) << 4) + dOff);
                acc2.x = fmaf(wr, a.x, acc2.x);
                acc2.y = fmaf(wr, a.y, acc2.y);
            }
        }
        asm volatile("s_waitcnt vmcnt(0)" ::: "memory");   // next chunk resident
        __syncthreads();                        // (C) buffer swap safe
    }

    // ---- combine 4 t-quarters, write (b,tile) partial record ----
    *(float2*)&fred[tq * 256 + dp * 2] = acc2;
    __syncthreads();
    if (tid < 256) {
        float s = fred[tid] + fred[256 + tid] + fred[512 + tid] + fred[768 + tid];
        size_t base = (size_t)bx * 258;
        part[base + tid] = s;
        if (tid == 0) part[base + 256] = fml[0];
        if (tid == 1) part[base + 257] = fml[1];
    }
}

__global__ __launch_bounds__(256)
void caa_combine(const float* __restrict__ part, float* __restrict__ out) {
    const int b = blockIdx.x, tid = threadIdx.x;
    __shared__ float sm[NT], sl[NT];
    if (tid < NT) {
        sm[tid] = part[(size_t)(b * NT + tid) * 258 + 256];
        sl[tid] = part[(size_t)(b * NT + tid) * 258 + 257];
    }
    __syncthreads();
    float M = sm[0];
    #pragma unroll
    for (int i = 1; i < NT; ++i) M = fmaxf(M, sm[i]);
    float S = 0.0f, o = 0.0f;
    #pragma unroll
    for (int i = 0; i < NT; ++i) {
        float e = __expf(sm[i] - M);
        S = fmaf(sl[i], e, S);
        o = fmaf(e, part[(size_t)(b * NT + i) * 258 + tid], o);
    }
    out[b * 256 + tid] = __fdividef(o, S);
}

extern "C" void kernel_launch(void* const* d_in, const int* in_sizes, int n_in,
                              void* d_out, int out_size, void* d_ws, size_t ws_size,
                              hipStream_t stream) {
    const float* seq = (const float*)d_in[0];
    const float* ctx = (const float*)d_in[1];
    const float* W1  = (const float*)d_in[2];
    const float* W2  = (const float*)d_in[3];
    float* part = (float*)d_ws;   // NT*BB*258*4 = 1,056,768 B of scratch

    (void)hipFuncSetAttribute((const void*)caa_main,
                              hipFuncAttributeMaxDynamicSharedMemorySize,
                              LDS_BYTES);

    caa_main<<<dim3(BB * NT), dim3(THREADS), LDS_BYTES, stream>>>(seq, ctx, W1, W2, part);
    caa_combine<<<dim3(BB), dim3(256), 0, stream>>>(part, (float*)d_out);
}

// Round 5
// 72.863 us; speedup vs baseline: 1.3810x; 1.3810x over previous
//
#include <hip/hip_runtime.h>
#include <cmath>

// Problem constants (fixed by the reference)
#define BB   64
#define TT   4096
#define DD1  256
#define DD2  128
#define UU   64
#define NT   32      // T tiles per batch row
#define TTILE 128    // rows per block
#define CH   32      // rows per chunk (staged in LDS)
#define NCH  4
#define THREADS 256

// A rows are 264 bf16 (=528 B): row-to-row bank rotation, 16B-aligned.
#define ROWB 528
#define HL   16896   // byte delta hi-array -> lo-array (32*528)

// LDS byte offsets (static shared, 36.5 KB -> 2 blocks/CU)
#define AH_OFF   0        // A hi [32][264] bf16 = 16896 B
#define AL_OFF   16896    // A lo
#define BIAS_OFF 33792    // 64 f32
#define WCH_OFF  34048    // 32 f32 softmax weights
#define LOGP_OFF 34176    // 64 f32 logit partials (2 u-halves x 32 rows)
#define ML_OFF   34432    // [0]=m [1]=l [2]=rescale [3]=pad
#define RED_OFF  34448    // 512 f32 (bias partials / final acc combine)
#define LDS_BYTES 36496

typedef short bf16x8 __attribute__((ext_vector_type(8)));
typedef float f32x4  __attribute__((ext_vector_type(4)));

__device__ __forceinline__ float tanh_fast(float x) {
    float ax = fabsf(x);
    float e  = __expf(-2.0f * ax);
    float t  = __fdividef(1.0f - e, 1.0f + e);
    return x < 0.0f ? -t : t;
}

// Convert float4 -> bf16 hi (truncate) / lo (residual) pairs, store 8B each.
__device__ __forceinline__ void cvt_write_row(char* smem, int row, int c4, float4 a) {
    unsigned b0 = __float_as_uint(a.x), b1 = __float_as_uint(a.y);
    unsigned b2 = __float_as_uint(a.z), b3 = __float_as_uint(a.w);
    unsigned h01 = (b0 >> 16) | (b1 & 0xffff0000u);
    unsigned h23 = (b2 >> 16) | (b3 & 0xffff0000u);
    float d0 = a.x - __uint_as_float(b0 & 0xffff0000u);
    float d1 = a.y - __uint_as_float(b1 & 0xffff0000u);
    float d2 = a.z - __uint_as_float(b2 & 0xffff0000u);
    float d3 = a.w - __uint_as_float(b3 & 0xffff0000u);
    unsigned l01 = (__float_as_uint(d0) >> 16) | (__float_as_uint(d1) & 0xffff0000u);
    unsigned l23 = (__float_as_uint(d2) >> 16) | (__float_as_uint(d3) & 0xffff0000u);
    *(uint2*)(smem + AH_OFF + row * ROWB + c4 * 8) = make_uint2(h01, h23);
    *(uint2*)(smem + AL_OFF + row * ROWB + c4 * 8) = make_uint2(l01, l23);
}

__device__ __forceinline__ void cvt_hilo(float4 f0, float4 f1, bf16x8& h8, bf16x8& l8) {
    float x[8] = {f0.x, f0.y, f0.z, f0.w, f1.x, f1.y, f1.z, f1.w};
    union { unsigned u[4]; bf16x8 v; } H, L;
    #pragma unroll
    for (int p = 0; p < 4; ++p) {
        unsigned a = __float_as_uint(x[2*p]), b = __float_as_uint(x[2*p+1]);
        H.u[p] = (a >> 16) | (b & 0xffff0000u);
        float d0 = x[2*p]   - __uint_as_float(a & 0xffff0000u);
        float d1 = x[2*p+1] - __uint_as_float(b & 0xffff0000u);
        L.u[p] = (__float_as_uint(d0) >> 16) | (__float_as_uint(d1) & 0xffff0000u);
    }
    h8 = H.v; l8 = L.v;
}

// W1 column u, k = kb..kb+7 -> hi/lo bf16x8 B-frag (stride UU floats)
__device__ __forceinline__ void load_bfrag(const float* __restrict__ W1, int kb, int u,
                                           bf16x8& bh, bf16x8& bl) {
    float4 x0, x1;
    x0.x = W1[(kb + 0) * UU + u]; x0.y = W1[(kb + 1) * UU + u];
    x0.z = W1[(kb + 2) * UU + u]; x0.w = W1[(kb + 3) * UU + u];
    x1.x = W1[(kb + 4) * UU + u]; x1.y = W1[(kb + 5) * UU + u];
    x1.z = W1[(kb + 6) * UU + u]; x1.w = W1[(kb + 7) * UU + u];
    cvt_hilo(x0, x1, bh, bl);
}

__global__ __launch_bounds__(THREADS, 2)   // 2 waves/EU -> 2 blocks/CU, VGPR cap 256
void caa_main(const float* __restrict__ seq, const float* __restrict__ ctx,
              const float* __restrict__ W1, const float* __restrict__ W2,
              float* __restrict__ part) {
    __shared__ __align__(16) char smem[LDS_BYTES];
    float* fml   = (float*)(smem + ML_OFF);
    float* fbias = (float*)(smem + BIAS_OFF);
    float* fwch  = (float*)(smem + WCH_OFF);
    float* flogp = (float*)(smem + LOGP_OFF);
    float* fred  = (float*)(smem + RED_OFF);

    const int tid = threadIdx.x;
    const int bx  = blockIdx.x;
    const int b    = bx >> 5, tile = bx & 31;
    const int w    = tid >> 6, l = tid & 63;
    const int l15  = l & 15,  kg = l >> 4;     // MFMA input: row/col = l15, k-octet = kg
    const int mf   = w & 1,   nh = w >> 1;     // wave -> m-frag (16 rows), u-half (32 u)

    const float* seqbase = seq + ((size_t)b * TT + (size_t)tile * TTILE) * DD1;

    // ---- chunk-0 global prefetch: 8 float4/thread (32 VGPR), coalesced ----
    // float4 index f = j*256+tid -> row f/64 = 4j+w, col16 = l
    float4 pf[8];
    {
        const float4* g = (const float4*)seqbase;
        #pragma unroll
        for (int j = 0; j < 8; ++j) pf[j] = g[j * THREADS + tid];
    }

    // ---- B-frags (W1_seq) resident in registers: 2 u-groups x 8 ks x hi/lo ----
    const int u0g = nh * 32 + l15, u1g = u0g + 16;
    bf16x8 b0h[8], b0l[8], b1h[8], b1l[8];
    #pragma unroll
    for (int ks = 0; ks < 8; ++ks) {
        int kb = ks * 32 + kg * 8;
        load_bfrag(W1, kb, u0g, b0h[ks], b0l[ks]);
        load_bfrag(W1, kb, u1g, b1h[ks], b1l[ks]);
    }

    // ---- bias partials: 4 c-chunks x 64 u ----
    {
        int cq = tid >> 6;
        float s = 0.f;
        const float* cb = ctx + b * DD2 + cq * 32;
        const float* wb = W1 + (size_t)(DD1 + cq * 32) * UU + l;
        #pragma unroll
        for (int c = 0; c < 32; ++c) s = fmaf(cb[c], wb[c * UU], s);
        fred[cq * 64 + l] = s;
    }
    if (tid == 0) { fml[0] = -INFINITY; fml[1] = 0.f; }
    __syncthreads();
    if (tid < 64) {
        fbias[tid] = fred[tid] + fred[64 + tid] + fred[128 + tid] + fred[192 + tid];
    }
    // ---- chunk 0 convert + LDS write ----
    #pragma unroll
    for (int j = 0; j < 8; ++j) cvt_write_row(smem, 4 * j + w, l, pf[j]);
    __syncthreads();

    const float bias0 = fbias[u0g], bias1 = fbias[u1g];
    const float w20 = W2[u0g], w21 = W2[u1g];

    const int aB = AH_OFF + (16 * mf + l15) * ROWB + kg * 16;
    float2 acc2 = make_float2(0.f, 0.f);       // weighted-sum acc: dims 2dp,2dp+1, quarter tq
    const int dp = tid & 127, tq = tid >> 7;

    for (int c = 0; c < NCH; ++c) {
        // issue next-chunk loads; they ride across all barriers, consumed at bottom
        if (c < NCH - 1) {
            const float4* g = (const float4*)(seqbase + (size_t)(c + 1) * CH * DD1);
            #pragma unroll
            for (int j = 0; j < 8; ++j) pf[j] = g[j * THREADS + tid];
        }
        // ---- split-bf16 MFMA GEMM: 32x64 tile, K=256; B from registers ----
        f32x4 acc0 = {0.f, 0.f, 0.f, 0.f}, acc1 = {0.f, 0.f, 0.f, 0.f};
        #pragma unroll
        for (int ks = 0; ks < 8; ++ks) {
            const int off = ks * 64;
            bf16x8 ah = *(const bf16x8*)(smem + aB + off);
            bf16x8 al = *(const bf16x8*)(smem + aB + HL + off);
            acc0 = __builtin_amdgcn_mfma_f32_16x16x32_bf16(ah, b0h[ks], acc0, 0, 0, 0);
            acc1 = __builtin_amdgcn_mfma_f32_16x16x32_bf16(ah, b1h[ks], acc1, 0, 0, 0);
            acc0 = __builtin_amdgcn_mfma_f32_16x16x32_bf16(ah, b0l[ks], acc0, 0, 0, 0);
            acc1 = __builtin_amdgcn_mfma_f32_16x16x32_bf16(ah, b1l[ks], acc1, 0, 0, 0);
            acc0 = __builtin_amdgcn_mfma_f32_16x16x32_bf16(al, b0h[ks], acc0, 0, 0, 0);
            acc1 = __builtin_amdgcn_mfma_f32_16x16x32_bf16(al, b1h[ks], acc1, 0, 0, 0);
        }
        // ---- epilogue: tanh + W2 dot; reduce over u (lane&15) ----
        float lp[4];
        #pragma unroll
        for (int r = 0; r < 4; ++r) {
            float e0 = tanh_fast(acc0[r] + bias0);
            float e1 = tanh_fast(acc1[r] + bias1);
            float p  = e0 * w20 + e1 * w21;
            p += __shfl_xor(p, 1, 64);
            p += __shfl_xor(p, 2, 64);
            p += __shfl_xor(p, 4, 64);
            p += __shfl_xor(p, 8, 64);
            lp[r] = p;
        }
        if (l15 == 0) {      // C/D row = kg*4 + r within m-frag (m89 layout, R3-verified)
            #pragma unroll
            for (int r = 0; r < 4; ++r) flogp[nh * 32 + 16 * mf + kg * 4 + r] = lp[r];
        }
        __syncthreads();                        // (A) logits visible
        // ---- online softmax over 32 chunk rows (lanes 0..31 of wave 0) ----
        if (tid < 32) {
            float lg = flogp[tid] + flogp[32 + tid];
            float mx = lg;
            mx = fmaxf(mx, __shfl_xor(mx, 1, 64));
            mx = fmaxf(mx, __shfl_xor(mx, 2, 64));
            mx = fmaxf(mx, __shfl_xor(mx, 4, 64));
            mx = fmaxf(mx, __shfl_xor(mx, 8, 64));
            mx = fmaxf(mx, __shfl_xor(mx, 16, 64));
            float mold = fml[0];
            float mnew = fmaxf(mold, mx);
            float rsc  = __expf(mold - mnew);   // first chunk: exp(-inf)=0
            float wv   = __expf(lg - mnew);
            float ss   = wv;
            ss += __shfl_xor(ss, 1, 64);
            ss += __shfl_xor(ss, 2, 64);
            ss += __shfl_xor(ss, 4, 64);
            ss += __shfl_xor(ss, 8, 64);
            ss += __shfl_xor(ss, 16, 64);
            fwch[tid] = wv;
            if (tid == 0) { fml[0] = mnew; fml[1] = fml[1] * rsc + ss; fml[2] = rsc; }
        }
        __syncthreads();                        // (B) weights visible
        // ---- weighted accumulation (reconstruct f32 = bf16hi + bf16lo) ----
        {
            float rsc = fml[2];
            acc2.x *= rsc; acc2.y *= rsc;
            #pragma unroll
            for (int i = 0; i < 16; ++i) {
                int row = tq * 16 + i;
                float wr = fwch[row];
                unsigned h  = *(const unsigned*)(smem + AH_OFF + row * ROWB + dp * 4);
                unsigned lo = *(const unsigned*)(smem + AL_OFF + row * ROWB + dp * 4);
                float f0 = __uint_as_float(h << 16) + __uint_as_float(lo << 16);
                float f1 = __uint_as_float(h & 0xffff0000u) + __uint_as_float(lo & 0xffff0000u);
                acc2.x = fmaf(wr, f0, acc2.x);
                acc2.y = fmaf(wr, f1, acc2.y);
            }
        }
        __syncthreads();                        // (C) done reading A
        if (c < NCH - 1) {
            #pragma unroll
            for (int j = 0; j < 8; ++j) cvt_write_row(smem, 4 * j + w, l, pf[j]);
            __syncthreads();                    // (D) new chunk visible
        }
    }

    // ---- combine 2 t-quarters, write (b,tile) partial record ----
    *(float2*)&fred[tq * 256 + dp * 2] = acc2;
    __syncthreads();
    {
        float s = fred[tid] + fred[256 + tid];
        size_t base = (size_t)bx * 258;
        part[base + tid] = s;
        if (tid == 0) part[base + 256] = fml[0];
        if (tid == 1) part[base + 257] = fml[1];
    }
}

__global__ __launch_bounds__(256)
void caa_combine(const float* __restrict__ part, float* __restrict__ out) {
    const int b = blockIdx.x, tid = threadIdx.x;
    __shared__ float sm[NT], sl[NT];
    if (tid < NT) {
        sm[tid] = part[(size_t)(b * NT + tid) * 258 + 256];
        sl[tid] = part[(size_t)(b * NT + tid) * 258 + 257];
    }
    __syncthreads();
    float M = sm[0];
    #pragma unroll
    for (int i = 1; i < NT; ++i) M = fmaxf(M, sm[i]);
    float S = 0.0f, o = 0.0f;
    #pragma unroll
    for (int i = 0; i < NT; ++i) {
        float e = __expf(sm[i] - M);
        S = fmaf(sl[i], e, S);
        o = fmaf(e, part[(size_t)(b * NT + i) * 258 + tid], o);
    }
    out[b * 256 + tid] = __fdividef(o, S);
}

extern "C" void kernel_launch(void* const* d_in, const int* in_sizes, int n_in,
                              void* d_out, int out_size, void* d_ws, size_t ws_size,
                              hipStream_t stream) {
    const float* seq = (const float*)d_in[0];
    const float* ctx = (const float*)d_in[1];
    const float* W1  = (const float*)d_in[2];
    const float* W2  = (const float*)d_in[3];
    float* part = (float*)d_ws;   // BB*NT*258*4 = 2,113,536 B of scratch

    caa_main<<<dim3(BB * NT), dim3(THREADS), 0, stream>>>(seq, ctx, W1, W2, part);
    caa_combine<<<dim3(BB), dim3(256), 0, stream>>>(part, (float*)d_out);
}